// Round 6
// baseline (80.797 us; speedup 1.0000x reference)
//
#include <hip/hip_runtime.h>
#include <hip/hip_cooperative_groups.h>

namespace cg = cooperative_groups;

// BotUpSaliency — single cooperative kernel, closed-form fire detection.
// While gx = clip(x-1,0,1) is identically zero the 16-step recurrence is
// per-ELEMENT decoupled and affine:
//   x <- x + 0.01*(a - x),  a = inp[px,k] + ck[k],  ck = 0.85-0.21-0.21*colsum(psi)
//   => x16 = a + (x0 - a)*0.99^16   (monotone toward a; trajectory max = x16)
// Phase 1 streams inp once (coalesced float4), evaluates the closed form, and
// flags firing (x16 > 0.98, threshold 1.0, margin >> rounding; NaN-safe).
// If no element fires anywhere, out == 0 exactly. The faithful tile-gated
// 16-step fallback runs inside the same kernel only when the flag is set —
// a spurious flag costs time, never correctness.
// Flag semantics: fired <=> *gf == MAGIC (no pre-zeroing launch needed; the
// 0xAA workspace poison can never equal MAGIC).

#define HH 512
#define WW 512
#define KK 12
#define NT 32
#define NTILE 2048      // 2 * 32 * 32 tiles
#define NBLK 1024
#define NTHR 256
#define TPB 2           // tiles per block in fallback
#define MAGIC 0x51A7F17E
#define NF4 1572864     // total float4s in (2,512,512,12)
#define OF4 131072      // total float4s in out (2,512,512)

constexpr float EPS_C = 0.01f;
constexpr float G1_C  = 0.21f;
constexpr float G2_C  = 2.5f;
constexpr float LY_C  = 1.2f;
constexpr float J0_C  = 0.8f;
constexpr float BETA  = 0.8514577710948756f;   // 0.99^16

__device__ __forceinline__ float gxf(float x) { return fminf(fmaxf(x - 1.0f, 0.0f), 1.0f); }
__device__ __forceinline__ float gyf(float y) {
  float yc = fmaxf(y, 0.0f);
  return (yc <= LY_C) ? G1_C * yc : fmaf(G2_C, yc - LY_C, G1_C * LY_C);
}
__device__ __forceinline__ int refl(int i, int n) {
  return i < 0 ? -i - 1 : (i >= n ? 2 * n - 1 - i : i);
}

__launch_bounds__(NTHR, 4)
__global__ void fused_kernel(const float* __restrict__ inp, const float* __restrict__ Wt,
                             const float* __restrict__ Jt, const float* __restrict__ psi,
                             float* __restrict__ xA, float* __restrict__ xB,
                             float* __restrict__ yb, float* __restrict__ oa,
                             int* __restrict__ flags, int* __restrict__ gf,
                             float* __restrict__ out) {
  cg::grid_group grid = cg::this_grid();
  const int tid = threadIdx.x;
  const int bid = blockIdx.x;

  __shared__ float ck12[12];
  __shared__ int sflag;
  __shared__ int wor[4];
  __shared__ float psis[KK * KK];
  __shared__ int nb[9];

  // ---- ck[k] = 0.85 - 0.21 - 0.21 * colsum(psi)_k  (once per block) ----
  if (tid < 12) {
    float s = 0.0f;
    #pragma unroll
    for (int c = 0; c < KK; ++c) s += psi[c * KK + tid];
    ck12[tid] = 0.85f - 0.21f - 0.21f * s;
  }
  __syncthreads();

  // ---- phase 1: coalesced closed-form fire scan over all elements ----
  bool fired = false;
  const float4* ip4 = (const float4*)inp;
  #pragma unroll 2
  for (int i = bid * NTHR + tid; i < NF4; i += NBLK * NTHR) {
    float4 v = ip4[i];
    int m = (i % 3) * 4;                 // element k = (4i+j) % 12 = 4*(i%3)+j
    float a0 = v.x + ck12[m + 0];
    float a1 = v.y + ck12[m + 1];
    float a2 = v.z + ck12[m + 2];
    float a3 = v.w + ck12[m + 3];
    float x0 = fmaf(0.01f - a0, BETA, a0);
    float x1 = fmaf(0.01f - a1, BETA, a1);
    float x2 = fmaf(0.01f - a2, BETA, a2);
    float x3 = fmaf(0.01f - a3, BETA, a3);
    // fire if x16 > 0.98 or NaN (NaN fails all ordered compares -> use !(<=))
    fired = fired || !(x0 <= 0.98f) || !(x1 <= 0.98f) ||
                     !(x2 <= 0.98f) || !(x3 <= 0.98f);
  }

  // ---- write out = 0 unconditionally (overwritten by fallback if fired) ----
  {
    int i = bid * NTHR + tid;
    if (i < OF4) ((float4*)out)[i] = make_float4(0.f, 0.f, 0.f, 0.f);
  }

  // ---- block OR, then device flag ----
  int wf = __any(fired) ? 1 : 0;
  if ((tid & 63) == 0) wor[tid >> 6] = wf;
  __syncthreads();
  if (tid == 0 && (wor[0] | wor[1] | wor[2] | wor[3]))
    atomicExch(gf, MAGIC);
  grid.sync();
  if (tid == 0) sflag = (atomicOr(gf, 0) == MAGIC) ? 1 : 0;
  __syncthreads();

  if (!sflag) return;    // uniform across grid: out is exactly zero

  // ================= faithful fallback (tile-gated, 16 steps) =================
  if (tid < KK * KK) psis[tid] = psi[tid];

  #pragma unroll 1
  for (int pp = 0; pp < TPB; ++pp) {
    int tile = bid * TPB + pp;
    int b = tile >> 10, rem = tile & 1023;
    int tyb = rem >> 5, txb = rem & 31;
    int r = tid >> 4, c = tid & 15;
    size_t base = (((size_t)b * HH + tyb * 16 + r) * WW + txb * 16 + c) * KK;
    #pragma unroll
    for (int q = 0; q < 3; ++q) {
      ((float4*)(xA + base))[q] = make_float4(0.01f, 0.01f, 0.01f, 0.01f);
      ((float4*)(yb + base))[q] = make_float4(1.0f, 1.0f, 1.0f, 1.0f);
      ((float4*)(oa + base))[q] = make_float4(0.0f, 0.0f, 0.0f, 0.0f);
    }
    if (tid == 0) flags[tile] = 0;
  }
  grid.sync();

  #pragma unroll 1
  for (int s = 0; s < 16; ++s) {
    const float* xin = (s & 1) ? xB : xA;
    float* xout = (s & 1) ? xA : xB;
    const int* fin = flags + (s & 1) * NTILE;
    int* fout = flags + ((s + 1) & 1) * NTILE;

    #pragma unroll 1
    for (int pp = 0; pp < TPB; ++pp) {
      int tile = bid * TPB + pp;
      int b = tile >> 10, rem = tile & 1023;
      int tyb = rem >> 5, txb = rem & 31;

      __syncthreads();
      if (tid < 9) {
        int dy = tid / 3 - 1, dx = tid % 3 - 1;
        int ty = min(max(tyb + dy, 0), NT - 1);
        int tx = min(max(txb + dx, 0), NT - 1);
        nb[tid] = fin[(b * NT + ty) * NT + tx];
      }
      __syncthreads();
      const int dense =
          (nb[0] | nb[1] | nb[2] | nb[3] | nb[4] | nb[5] | nb[6] | nb[7] | nb[8]) & 1;

      const int r = tid >> 4, c = tid & 15;
      const int gh = tyb * 16 + r, gw = txb * 16 + c;
      const size_t base = (((size_t)b * HH + gh) * WW + gw) * KK;

      float accJ[KK], accW[KK];
      #pragma unroll
      for (int k = 0; k < KK; ++k) { accJ[k] = 0.0f; accW[k] = 0.0f; }
      float i_norm = 0.85f;

      if (dense) {
        #pragma unroll 1
        for (int di = 0; di < 15; ++di) {
          int ih = refl(gh - 7 + di, HH);
          #pragma unroll 1
          for (int dj = 0; dj < 15; ++dj) {
            int iw = refl(gw - 7 + dj, WW);
            const float* p = xin + (((size_t)b * HH + ih) * WW + iw) * KK;
            const float* wj = Jt + (size_t)(di * 15 + dj) * KK * KK;
            const float* wi = Wt + (size_t)(di * 15 + dj) * KK * KK;
            #pragma unroll 1
            for (int cc = 0; cc < KK; ++cc) {
              float g = gxf(p[cc]);
              if (g > 0.0f) {
                #pragma unroll
                for (int k = 0; k < KK; ++k) {
                  accJ[k] = fmaf(g, wj[cc * KK + k], accJ[k]);
                  accW[k] = fmaf(g, wi[cc * KK + k], accW[k]);
                }
              }
            }
          }
        }
        float box = 0.0f;
        #pragma unroll 1
        for (int u = 0; u < 5; ++u) {
          int ih = gh - 2 + u;
          if (ih < 0 || ih >= HH) continue;
          #pragma unroll 1
          for (int v = 0; v < 5; ++v) {
            int iw = gw - 2 + v;
            if (iw < 0 || iw >= WW) continue;
            const float* p = xin + (((size_t)b * HH + ih) * WW + iw) * KK;
            float sv = 0.0f;
            #pragma unroll
            for (int cc = 0; cc < KK; ++cc) sv += gxf(p[cc]);
            box += sv;
          }
        }
        float bn = box * (1.0f / 25.0f);
        i_norm = 0.85f - 2.0f * bn * bn;
      }

      float xv[KK], yv[KK], inv[KK];
      #pragma unroll
      for (int q = 0; q < 3; ++q) {
        float4 v = ((const float4*)(xin + base))[q];
        xv[q*4+0]=v.x; xv[q*4+1]=v.y; xv[q*4+2]=v.z; xv[q*4+3]=v.w;
        float4 u = ((const float4*)(yb + base))[q];
        yv[q*4+0]=u.x; yv[q*4+1]=u.y; yv[q*4+2]=u.z; yv[q*4+3]=u.w;
        float4 w = ((const float4*)(inp + base))[q];
        inv[q*4+0]=w.x; inv[q*4+1]=w.y; inv[q*4+2]=w.z; inv[q*4+3]=w.w;
      }
      float gyv[KK];
      #pragma unroll
      for (int k = 0; k < KK; ++k) gyv[k] = gyf(yv[k]);

      float xn[KK], yn[KK], gn[KK];
      bool anyg = false;
      #pragma unroll
      for (int k = 0; k < KK; ++k) {
        float gxk = gxf(xv[k]);
        float psit = 0.0f;
        #pragma unroll
        for (int cc = 0; cc < KK; ++cc) psit = fmaf(gyv[cc], psis[cc * KK + k], psit);
        float ynew = yv[k] + EPS_C * (-yv[k] + gxk + accW[k] + 1.0f);
        float xnew = xv[k] + EPS_C * (J0_C * gxk + accJ[k] + inv[k] + i_norm
                                      - xv[k] - gyv[k] - psit);
        xn[k] = xnew; yn[k] = ynew; gn[k] = gxf(xnew);
        anyg = anyg || (gn[k] > 0.0f);
      }

      #pragma unroll
      for (int q = 0; q < 3; ++q) {
        float4 v; v.x=xn[q*4+0]; v.y=xn[q*4+1]; v.z=xn[q*4+2]; v.w=xn[q*4+3];
        ((float4*)(xout + base))[q] = v;
        float4 u; u.x=yn[q*4+0]; u.y=yn[q*4+1]; u.z=yn[q*4+2]; u.w=yn[q*4+3];
        ((float4*)(yb + base))[q] = u;
        float4 o = ((const float4*)(oa + base))[q];
        o.x += gn[q*4+0]; o.y += gn[q*4+1]; o.z += gn[q*4+2]; o.w += gn[q*4+3];
        ((float4*)(oa + base))[q] = o;
      }

      int wfb = __any(anyg) ? 1 : 0;
      if ((tid & 63) == 0) wor[tid >> 6] = wfb;
      __syncthreads();
      if (tid == 0) fout[tile] = wor[0] | wor[1] | wor[2] | wor[3];
    }
    grid.sync();
  }

  // final: out = max_k (oa / 16)
  #pragma unroll 1
  for (int pp = 0; pp < TPB; ++pp) {
    int tile = bid * TPB + pp;
    int b = tile >> 10, rem = tile & 1023;
    int tyb = rem >> 5, txb = rem & 31;
    int r = tid >> 4, c = tid & 15;
    int gh = tyb * 16 + r, gw = txb * 16 + c;
    const float* o = oa + (((size_t)b * HH + gh) * WW + gw) * KK;
    float m = o[0];
    #pragma unroll
    for (int cc = 1; cc < KK; ++cc) m = fmaxf(m, o[cc]);
    out[((size_t)b * HH + gh) * WW + gw] = m * (1.0f / 16.0f);
  }
}

extern "C" void kernel_launch(void* const* d_in, const int* in_sizes, int n_in,
                              void* d_out, int out_size, void* d_ws, size_t ws_size,
                              hipStream_t stream) {
  const float* inp = (const float*)d_in[0];   // (2,512,512,12)
  const float* Wt  = (const float*)d_in[1];   // (15,15,12,12) HWIO
  const float* Jt  = (const float*)d_in[2];   // (15,15,12,12) HWIO
  const float* psi = (const float*)d_in[3];   // (1,1,12,12)

  float* ws = (float*)d_ws;
  const size_t N = (size_t)2 * HH * WW * KK;      // 6,291,456 floats
  float* xA = ws;
  float* xB = ws + N;
  float* yb = ws + 2 * N;
  float* oa = ws + 3 * N;
  int* flags = (int*)(ws + 4 * N);                // 2 * 2048 ints
  int* gf = flags + 2 * NTILE;
  float* out = (float*)d_out;

  void* args[] = {(void*)&inp, (void*)&Wt, (void*)&Jt, (void*)&psi,
                  (void*)&xA, (void*)&xB, (void*)&yb, (void*)&oa,
                  (void*)&flags, (void*)&gf, (void*)&out};
  hipLaunchCooperativeKernel((void*)fused_kernel, dim3(NBLK), dim3(NTHR),
                             args, 0, stream);
}

// Round 7
// 31.901 us; speedup vs baseline: 2.5328x; 2.5328x over previous
//
#include <hip/hip_runtime.h>
#include <hip/hip_cooperative_groups.h>

namespace cg = cooperative_groups;

// BotUpSaliency — two-dispatch version (no grid.sync on the hot path).
// While gx = clip(x-1,0,1) is identically zero the 16-step recurrence is
// per-element decoupled and affine:
//   x <- x + 0.01*(a - x),  a = inp[px,k] + ck[k],  ck = 0.85-0.21-0.21*colsum(psi)
//   => x16 = a(1-B) + 0.01*B,  B = 0.99^16  (monotone; trajectory max = x16)
// Fire detection threshold on x16 of 0.98 (true threshold 1.0) translates to
// a >= ATH; we use the conservative scalar test  v >= ATH - max_k(ck)  so the
// scan needs no per-element k lookup. Over-detection only triggers the
// faithful fallback (slow but correct), never wrongness.
//
// Dispatch 1 (scan, non-cooperative): stream inp once, zero out, write one
// flag per block into its own slot (overwrite -> no reset, no atomics).
// Dispatch 2 (fallback, cooperative): all blocks OR the flags (uniform
// decision), early-exit when clear; full tile-gated 16-step solver otherwise.

#define HH 512
#define WW 512
#define KK 12
#define NT 32
#define NTILE 2048      // 2 * 32 * 32 tiles
#define NBLK 1024
#define NTHR 256
#define TPB 2           // tiles per block in fallback
#define NF4 1572864     // float4s in (2,512,512,12)
#define OF4 131072      // float4s in out (2,512,512)

constexpr float EPS_C = 0.01f;
constexpr float G1_C  = 0.21f;
constexpr float G2_C  = 2.5f;
constexpr float LY_C  = 1.2f;
constexpr float J0_C  = 0.8f;
constexpr float BETA  = 0.8514577710948756f;               // 0.99^16
constexpr float ATH   = (0.98f - 0.01f * BETA) / (1.0f - BETA);  // a-threshold

__device__ __forceinline__ float gxf(float x) { return fminf(fmaxf(x - 1.0f, 0.0f), 1.0f); }
__device__ __forceinline__ float gyf(float y) {
  float yc = fmaxf(y, 0.0f);
  return (yc <= LY_C) ? G1_C * yc : fmaf(G2_C, yc - LY_C, G1_C * LY_C);
}
__device__ __forceinline__ int refl(int i, int n) {
  return i < 0 ? -i - 1 : (i >= n ? 2 * n - 1 - i : i);
}

__launch_bounds__(NTHR)
__global__ void scan_kernel(const float* __restrict__ inp, const float* __restrict__ psi,
                            int* __restrict__ bflags, float* __restrict__ out) {
  const int tid = threadIdx.x, bid = blockIdx.x;
  __shared__ float sck[12];
  __shared__ float svth;
  __shared__ int wor[4];

  if (tid < 12) {
    float s = 0.0f;
    #pragma unroll
    for (int c = 0; c < KK; ++c) s += psi[c * KK + tid];
    sck[tid] = 0.85f - 0.21f - 0.21f * s;
  }
  __syncthreads();
  if (tid == 0) {
    float m = sck[0];
    #pragma unroll
    for (int k = 1; k < 12; ++k) m = fmaxf(m, sck[k]);
    svth = ATH - m;        // fire if any inp element >= svth (conservative)
  }
  __syncthreads();
  const float vth = svth;

  bool fired = false;
  const float4* ip4 = (const float4*)inp;
  #pragma unroll 2
  for (int i = bid * NTHR + tid; i < NF4; i += NBLK * NTHR) {
    float4 v = ip4[i];
    // fire when >= vth or NaN: !(x < vth)
    fired = fired || !(v.x < vth) || !(v.y < vth) || !(v.z < vth) || !(v.w < vth);
  }

  // zero the output (overwritten by fallback if fired)
  for (int i = bid * NTHR + tid; i < OF4; i += NBLK * NTHR)
    ((float4*)out)[i] = make_float4(0.f, 0.f, 0.f, 0.f);

  int wf = __any(fired) ? 1 : 0;
  if ((tid & 63) == 0) wor[tid >> 6] = wf;
  __syncthreads();
  if (tid == 0) bflags[bid] = wor[0] | wor[1] | wor[2] | wor[3];
}

__launch_bounds__(NTHR, 4)
__global__ void fallback_kernel(const float* __restrict__ inp, const float* __restrict__ Wt,
                                const float* __restrict__ Jt, const float* __restrict__ psi,
                                float* __restrict__ xA, float* __restrict__ xB,
                                float* __restrict__ yb, float* __restrict__ oa,
                                int* __restrict__ flags, const int* __restrict__ bflags,
                                float* __restrict__ out) {
  cg::grid_group grid = cg::this_grid();
  const int tid = threadIdx.x;
  const int bid = blockIdx.x;

  __shared__ int wor[4];
  __shared__ float psis[KK * KK];
  __shared__ int nb[9];

  // ---- uniform global decision: OR of all 1024 per-block flags ----
  int f = 0;
  #pragma unroll
  for (int q = 0; q < NBLK / NTHR; ++q) f |= bflags[q * NTHR + tid];
  int wf = __any(f) ? 1 : 0;
  if ((tid & 63) == 0) wor[tid >> 6] = wf;
  __syncthreads();
  if (!(wor[0] | wor[1] | wor[2] | wor[3])) return;   // uniform across grid

  // ================= faithful fallback (tile-gated, 16 steps) =================
  if (tid < KK * KK) psis[tid] = psi[tid];

  #pragma unroll 1
  for (int pp = 0; pp < TPB; ++pp) {
    int tile = bid * TPB + pp;
    int b = tile >> 10, rem = tile & 1023;
    int tyb = rem >> 5, txb = rem & 31;
    int r = tid >> 4, c = tid & 15;
    size_t base = (((size_t)b * HH + tyb * 16 + r) * WW + txb * 16 + c) * KK;
    #pragma unroll
    for (int q = 0; q < 3; ++q) {
      ((float4*)(xA + base))[q] = make_float4(0.01f, 0.01f, 0.01f, 0.01f);
      ((float4*)(yb + base))[q] = make_float4(1.0f, 1.0f, 1.0f, 1.0f);
      ((float4*)(oa + base))[q] = make_float4(0.0f, 0.0f, 0.0f, 0.0f);
    }
    if (tid == 0) flags[tile] = 0;
  }
  grid.sync();

  #pragma unroll 1
  for (int s = 0; s < 16; ++s) {
    const float* xin = (s & 1) ? xB : xA;
    float* xout = (s & 1) ? xA : xB;
    const int* fin = flags + (s & 1) * NTILE;
    int* fout = flags + ((s + 1) & 1) * NTILE;

    #pragma unroll 1
    for (int pp = 0; pp < TPB; ++pp) {
      int tile = bid * TPB + pp;
      int b = tile >> 10, rem = tile & 1023;
      int tyb = rem >> 5, txb = rem & 31;

      __syncthreads();
      if (tid < 9) {
        int dy = tid / 3 - 1, dx = tid % 3 - 1;
        int ty = min(max(tyb + dy, 0), NT - 1);
        int tx = min(max(txb + dx, 0), NT - 1);
        nb[tid] = fin[(b * NT + ty) * NT + tx];
      }
      __syncthreads();
      const int dense =
          (nb[0] | nb[1] | nb[2] | nb[3] | nb[4] | nb[5] | nb[6] | nb[7] | nb[8]) & 1;

      const int r = tid >> 4, c = tid & 15;
      const int gh = tyb * 16 + r, gw = txb * 16 + c;
      const size_t base = (((size_t)b * HH + gh) * WW + gw) * KK;

      float accJ[KK], accW[KK];
      #pragma unroll
      for (int k = 0; k < KK; ++k) { accJ[k] = 0.0f; accW[k] = 0.0f; }
      float i_norm = 0.85f;

      if (dense) {
        #pragma unroll 1
        for (int di = 0; di < 15; ++di) {
          int ih = refl(gh - 7 + di, HH);
          #pragma unroll 1
          for (int dj = 0; dj < 15; ++dj) {
            int iw = refl(gw - 7 + dj, WW);
            const float* p = xin + (((size_t)b * HH + ih) * WW + iw) * KK;
            const float* wj = Jt + (size_t)(di * 15 + dj) * KK * KK;
            const float* wi = Wt + (size_t)(di * 15 + dj) * KK * KK;
            #pragma unroll 1
            for (int cc = 0; cc < KK; ++cc) {
              float g = gxf(p[cc]);
              if (g > 0.0f) {
                #pragma unroll
                for (int k = 0; k < KK; ++k) {
                  accJ[k] = fmaf(g, wj[cc * KK + k], accJ[k]);
                  accW[k] = fmaf(g, wi[cc * KK + k], accW[k]);
                }
              }
            }
          }
        }
        float box = 0.0f;
        #pragma unroll 1
        for (int u = 0; u < 5; ++u) {
          int ih = gh - 2 + u;
          if (ih < 0 || ih >= HH) continue;
          #pragma unroll 1
          for (int v = 0; v < 5; ++v) {
            int iw = gw - 2 + v;
            if (iw < 0 || iw >= WW) continue;
            const float* p = xin + (((size_t)b * HH + ih) * WW + iw) * KK;
            float sv = 0.0f;
            #pragma unroll
            for (int cc = 0; cc < KK; ++cc) sv += gxf(p[cc]);
            box += sv;
          }
        }
        float bn = box * (1.0f / 25.0f);
        i_norm = 0.85f - 2.0f * bn * bn;
      }

      float xv[KK], yv[KK], inv[KK];
      #pragma unroll
      for (int q = 0; q < 3; ++q) {
        float4 v = ((const float4*)(xin + base))[q];
        xv[q*4+0]=v.x; xv[q*4+1]=v.y; xv[q*4+2]=v.z; xv[q*4+3]=v.w;
        float4 u = ((const float4*)(yb + base))[q];
        yv[q*4+0]=u.x; yv[q*4+1]=u.y; yv[q*4+2]=u.z; yv[q*4+3]=u.w;
        float4 w = ((const float4*)(inp + base))[q];
        inv[q*4+0]=w.x; inv[q*4+1]=w.y; inv[q*4+2]=w.z; inv[q*4+3]=w.w;
      }
      float gyv[KK];
      #pragma unroll
      for (int k = 0; k < KK; ++k) gyv[k] = gyf(yv[k]);

      float xn[KK], yn[KK], gn[KK];
      bool anyg = false;
      #pragma unroll
      for (int k = 0; k < KK; ++k) {
        float gxk = gxf(xv[k]);
        float psit = 0.0f;
        #pragma unroll
        for (int cc = 0; cc < KK; ++cc) psit = fmaf(gyv[cc], psis[cc * KK + k], psit);
        float ynew = yv[k] + EPS_C * (-yv[k] + gxk + accW[k] + 1.0f);
        float xnew = xv[k] + EPS_C * (J0_C * gxk + accJ[k] + inv[k] + i_norm
                                      - xv[k] - gyv[k] - psit);
        xn[k] = xnew; yn[k] = ynew; gn[k] = gxf(xnew);
        anyg = anyg || (gn[k] > 0.0f);
      }

      #pragma unroll
      for (int q = 0; q < 3; ++q) {
        float4 v; v.x=xn[q*4+0]; v.y=xn[q*4+1]; v.z=xn[q*4+2]; v.w=xn[q*4+3];
        ((float4*)(xout + base))[q] = v;
        float4 u; u.x=yn[q*4+0]; u.y=yn[q*4+1]; u.z=yn[q*4+2]; u.w=yn[q*4+3];
        ((float4*)(yb + base))[q] = u;
        float4 o = ((const float4*)(oa + base))[q];
        o.x += gn[q*4+0]; o.y += gn[q*4+1]; o.z += gn[q*4+2]; o.w += gn[q*4+3];
        ((float4*)(oa + base))[q] = o;
      }

      int wfb = __any(anyg) ? 1 : 0;
      if ((tid & 63) == 0) wor[tid >> 6] = wfb;
      __syncthreads();
      if (tid == 0) fout[tile] = wor[0] | wor[1] | wor[2] | wor[3];
    }
    grid.sync();
  }

  // final: out = max_k (oa / 16)
  #pragma unroll 1
  for (int pp = 0; pp < TPB; ++pp) {
    int tile = bid * TPB + pp;
    int b = tile >> 10, rem = tile & 1023;
    int tyb = rem >> 5, txb = rem & 31;
    int r = tid >> 4, c = tid & 15;
    int gh = tyb * 16 + r, gw = txb * 16 + c;
    const float* o = oa + (((size_t)b * HH + gh) * WW + gw) * KK;
    float m = o[0];
    #pragma unroll
    for (int cc = 1; cc < KK; ++cc) m = fmaxf(m, o[cc]);
    out[((size_t)b * HH + gh) * WW + gw] = m * (1.0f / 16.0f);
  }
}

extern "C" void kernel_launch(void* const* d_in, const int* in_sizes, int n_in,
                              void* d_out, int out_size, void* d_ws, size_t ws_size,
                              hipStream_t stream) {
  const float* inp = (const float*)d_in[0];   // (2,512,512,12)
  const float* Wt  = (const float*)d_in[1];   // (15,15,12,12) HWIO
  const float* Jt  = (const float*)d_in[2];   // (15,15,12,12) HWIO
  const float* psi = (const float*)d_in[3];   // (1,1,12,12)

  float* ws = (float*)d_ws;
  const size_t N = (size_t)2 * HH * WW * KK;      // 6,291,456 floats
  float* xA = ws;
  float* xB = ws + N;
  float* yb = ws + 2 * N;
  float* oa = ws + 3 * N;
  int* flags  = (int*)(ws + 4 * N);               // 2 * NTILE ints (fallback gates)
  int* bflags = flags + 2 * NTILE;                // NBLK ints (scan per-block flags)
  float* out = (float*)d_out;

  scan_kernel<<<dim3(NBLK), dim3(NTHR), 0, stream>>>(inp, psi, bflags, out);

  void* args[] = {(void*)&inp, (void*)&Wt, (void*)&Jt, (void*)&psi,
                  (void*)&xA, (void*)&xB, (void*)&yb, (void*)&oa,
                  (void*)&flags, (void*)&bflags, (void*)&out};
  hipLaunchCooperativeKernel((void*)fallback_kernel, dim3(NBLK), dim3(NTHR),
                             args, 0, stream);
}

// Round 8
// 14.241 us; speedup vs baseline: 5.6734x; 2.2400x over previous
//
#include <hip/hip_runtime.h>

// BotUpSaliency — two plain dispatches, no cooperative launch.
// While gx = clip(x-1,0,1) is identically zero the 16-step recurrence is
// per-element decoupled and affine:
//   x <- x + 0.01*(a - x),  a = inp[px,k] + ck[k],  ck = 0.85-0.21-0.21*colsum(psi)
//   => x16 = a(1-B) + 0.01*B,  B = 0.99^16  (monotone; trajectory max = x16)
// Fire detection: conservative scalar test  v >= ATH - max_k(ck)  (threshold on
// x16 of 0.98 vs true 1.0). Over-detection only triggers the faithful fallback
// (slow but correct), never wrongness.
//
// Dispatch 1 (scan): stream inp once (coalesced float4), zero out, set
// gf=MAGIC via atomicExch ONLY if fired (clean path never writes gf -> poison
// 0xAA... != MAGIC is stable & deterministic), and re-init the software-
// barrier counters (cnt=0, gen=0) for the fallback's fired path.
// Dispatch 2 (fallback, plain): read gf, uniformly exit if != MAGIC.
// Fired path: tile-gated 16-step solver with a software sense-reversing
// grid barrier; grid=512 with __launch_bounds__(256,2) -> 2 blocks/CU ->
// all 512 blocks co-resident by capacity.

#define HH 512
#define WW 512
#define KK 12
#define NT 32
#define NTILE 2048      // 2 * 32 * 32 tiles
#define NBLK 1024       // scan grid
#define NBLK2 512       // fallback grid (co-resident: 2 blocks/CU x 256 CU)
#define NTHR 256
#define TPB 4           // tiles per fallback block (512*4 = 2048)
#define NF4 1572864     // float4s in (2,512,512,12)
#define OF4 131072      // float4s in out (2,512,512)
#define MAGIC 0x51A7F17E

constexpr float EPS_C = 0.01f;
constexpr float G1_C  = 0.21f;
constexpr float G2_C  = 2.5f;
constexpr float LY_C  = 1.2f;
constexpr float J0_C  = 0.8f;
constexpr float BETA  = 0.8514577710948756f;               // 0.99^16
constexpr float ATH   = (0.98f - 0.01f * BETA) / (1.0f - BETA);  // a-threshold

__device__ __forceinline__ float gxf(float x) { return fminf(fmaxf(x - 1.0f, 0.0f), 1.0f); }
__device__ __forceinline__ float gyf(float y) {
  float yc = fmaxf(y, 0.0f);
  return (yc <= LY_C) ? G1_C * yc : fmaf(G2_C, yc - LY_C, G1_C * LY_C);
}
__device__ __forceinline__ int refl(int i, int n) {
  return i < 0 ? -i - 1 : (i >= n ? 2 * n - 1 - i : i);
}

// software grid barrier (sense-reversing via generation counter);
// only ever executed on the (never-taken) fired path.
__device__ __forceinline__ void gbar(int* cnt, int* gen) {
  __syncthreads();
  if (threadIdx.x == 0) {
    __threadfence();                      // make this block's writes visible
    int g = __hip_atomic_load(gen, __ATOMIC_ACQUIRE, __HIP_MEMORY_SCOPE_AGENT);
    int a = __hip_atomic_fetch_add(cnt, 1, __ATOMIC_ACQ_REL, __HIP_MEMORY_SCOPE_AGENT);
    if (a == NBLK2 - 1) {
      __hip_atomic_store(cnt, 0, __ATOMIC_RELAXED, __HIP_MEMORY_SCOPE_AGENT);
      __hip_atomic_fetch_add(gen, 1, __ATOMIC_RELEASE, __HIP_MEMORY_SCOPE_AGENT);
    } else {
      while (__hip_atomic_load(gen, __ATOMIC_ACQUIRE, __HIP_MEMORY_SCOPE_AGENT) == g) { }
    }
    __threadfence();                      // acquire other blocks' writes
  }
  __syncthreads();
}

__launch_bounds__(NTHR)
__global__ void scan_kernel(const float* __restrict__ inp, const float* __restrict__ psi,
                            int* __restrict__ gf, int* __restrict__ cnt,
                            int* __restrict__ gen, float* __restrict__ out) {
  const int tid = threadIdx.x, bid = blockIdx.x;
  __shared__ float sck[12];
  __shared__ float svth;
  __shared__ int wor[4];

  if (bid == 0 && tid == 0) { *cnt = 0; *gen = 0; }   // barrier re-init (each call)

  if (tid < 12) {
    float s = 0.0f;
    #pragma unroll
    for (int c = 0; c < KK; ++c) s += psi[c * KK + tid];
    sck[tid] = 0.85f - 0.21f - 0.21f * s;
  }
  __syncthreads();
  if (tid == 0) {
    float m = sck[0];
    #pragma unroll
    for (int k = 1; k < 12; ++k) m = fmaxf(m, sck[k]);
    svth = ATH - m;        // fire if any inp element >= svth (conservative)
  }
  __syncthreads();
  const float vth = svth;

  bool fired = false;
  const float4* ip4 = (const float4*)inp;
  #pragma unroll 2
  for (int i = bid * NTHR + tid; i < NF4; i += NBLK * NTHR) {
    float4 v = ip4[i];
    // fire when >= vth or NaN: !(x < vth)
    fired = fired || !(v.x < vth) || !(v.y < vth) || !(v.z < vth) || !(v.w < vth);
  }

  // zero the output (overwritten by fallback if fired)
  for (int i = bid * NTHR + tid; i < OF4; i += NBLK * NTHR)
    ((float4*)out)[i] = make_float4(0.f, 0.f, 0.f, 0.f);

  int wf = __any(fired) ? 1 : 0;
  if ((tid & 63) == 0) wor[tid >> 6] = wf;
  __syncthreads();
  if (tid == 0 && (wor[0] | wor[1] | wor[2] | wor[3]))
    atomicExch(gf, MAGIC);               // only ever written when fired
}

__launch_bounds__(NTHR, 2)
__global__ void fallback_kernel(const float* __restrict__ inp, const float* __restrict__ Wt,
                                const float* __restrict__ Jt, const float* __restrict__ psi,
                                float* __restrict__ xA, float* __restrict__ xB,
                                float* __restrict__ yb, float* __restrict__ oa,
                                int* __restrict__ flags, int* __restrict__ gf,
                                int* __restrict__ cnt, int* __restrict__ gen,
                                float* __restrict__ out) {
  const int tid = threadIdx.x;
  const int bid = blockIdx.x;

  __shared__ int sflag;
  __shared__ int wor[4];
  __shared__ float psis[KK * KK];
  __shared__ int nb[9];

  if (tid == 0)
    sflag = (__hip_atomic_load(gf, __ATOMIC_ACQUIRE, __HIP_MEMORY_SCOPE_AGENT) == MAGIC);
  __syncthreads();
  if (!sflag) return;                    // uniform across grid: out stays zero

  // ================= faithful fallback (tile-gated, 16 steps) =================
  if (tid < KK * KK) psis[tid] = psi[tid];

  #pragma unroll 1
  for (int pp = 0; pp < TPB; ++pp) {
    int tile = bid * TPB + pp;
    int b = tile >> 10, rem = tile & 1023;
    int tyb = rem >> 5, txb = rem & 31;
    int r = tid >> 4, c = tid & 15;
    size_t base = (((size_t)b * HH + tyb * 16 + r) * WW + txb * 16 + c) * KK;
    #pragma unroll
    for (int q = 0; q < 3; ++q) {
      ((float4*)(xA + base))[q] = make_float4(0.01f, 0.01f, 0.01f, 0.01f);
      ((float4*)(yb + base))[q] = make_float4(1.0f, 1.0f, 1.0f, 1.0f);
      ((float4*)(oa + base))[q] = make_float4(0.0f, 0.0f, 0.0f, 0.0f);
    }
    if (tid == 0) flags[tile] = 0;
  }
  gbar(cnt, gen);

  #pragma unroll 1
  for (int s = 0; s < 16; ++s) {
    const float* xin = (s & 1) ? xB : xA;
    float* xout = (s & 1) ? xA : xB;
    const int* fin = flags + (s & 1) * NTILE;
    int* fout = flags + ((s + 1) & 1) * NTILE;

    #pragma unroll 1
    for (int pp = 0; pp < TPB; ++pp) {
      int tile = bid * TPB + pp;
      int b = tile >> 10, rem = tile & 1023;
      int tyb = rem >> 5, txb = rem & 31;

      __syncthreads();
      if (tid < 9) {
        int dy = tid / 3 - 1, dx = tid % 3 - 1;
        int ty = min(max(tyb + dy, 0), NT - 1);
        int tx = min(max(txb + dx, 0), NT - 1);
        nb[tid] = fin[(b * NT + ty) * NT + tx];
      }
      __syncthreads();
      const int dense =
          (nb[0] | nb[1] | nb[2] | nb[3] | nb[4] | nb[5] | nb[6] | nb[7] | nb[8]) & 1;

      const int r = tid >> 4, c = tid & 15;
      const int gh = tyb * 16 + r, gw = txb * 16 + c;
      const size_t base = (((size_t)b * HH + gh) * WW + gw) * KK;

      float accJ[KK], accW[KK];
      #pragma unroll
      for (int k = 0; k < KK; ++k) { accJ[k] = 0.0f; accW[k] = 0.0f; }
      float i_norm = 0.85f;

      if (dense) {
        #pragma unroll 1
        for (int di = 0; di < 15; ++di) {
          int ih = refl(gh - 7 + di, HH);
          #pragma unroll 1
          for (int dj = 0; dj < 15; ++dj) {
            int iw = refl(gw - 7 + dj, WW);
            const float* p = xin + (((size_t)b * HH + ih) * WW + iw) * KK;
            const float* wj = Jt + (size_t)(di * 15 + dj) * KK * KK;
            const float* wi = Wt + (size_t)(di * 15 + dj) * KK * KK;
            #pragma unroll 1
            for (int cc = 0; cc < KK; ++cc) {
              float g = gxf(p[cc]);
              if (g > 0.0f) {
                #pragma unroll
                for (int k = 0; k < KK; ++k) {
                  accJ[k] = fmaf(g, wj[cc * KK + k], accJ[k]);
                  accW[k] = fmaf(g, wi[cc * KK + k], accW[k]);
                }
              }
            }
          }
        }
        float box = 0.0f;
        #pragma unroll 1
        for (int u = 0; u < 5; ++u) {
          int ih = gh - 2 + u;
          if (ih < 0 || ih >= HH) continue;
          #pragma unroll 1
          for (int v = 0; v < 5; ++v) {
            int iw = gw - 2 + v;
            if (iw < 0 || iw >= WW) continue;
            const float* p = xin + (((size_t)b * HH + ih) * WW + iw) * KK;
            float sv = 0.0f;
            #pragma unroll
            for (int cc = 0; cc < KK; ++cc) sv += gxf(p[cc]);
            box += sv;
          }
        }
        float bn = box * (1.0f / 25.0f);
        i_norm = 0.85f - 2.0f * bn * bn;
      }

      float xv[KK], yv[KK], inv[KK];
      #pragma unroll
      for (int q = 0; q < 3; ++q) {
        float4 v = ((const float4*)(xin + base))[q];
        xv[q*4+0]=v.x; xv[q*4+1]=v.y; xv[q*4+2]=v.z; xv[q*4+3]=v.w;
        float4 u = ((const float4*)(yb + base))[q];
        yv[q*4+0]=u.x; yv[q*4+1]=u.y; yv[q*4+2]=u.z; yv[q*4+3]=u.w;
        float4 w = ((const float4*)(inp + base))[q];
        inv[q*4+0]=w.x; inv[q*4+1]=w.y; inv[q*4+2]=w.z; inv[q*4+3]=w.w;
      }
      float gyv[KK];
      #pragma unroll
      for (int k = 0; k < KK; ++k) gyv[k] = gyf(yv[k]);

      float xn[KK], yn[KK], gn[KK];
      bool anyg = false;
      #pragma unroll
      for (int k = 0; k < KK; ++k) {
        float gxk = gxf(xv[k]);
        float psit = 0.0f;
        #pragma unroll
        for (int cc = 0; cc < KK; ++cc) psit = fmaf(gyv[cc], psis[cc * KK + k], psit);
        float ynew = yv[k] + EPS_C * (-yv[k] + gxk + accW[k] + 1.0f);
        float xnew = xv[k] + EPS_C * (J0_C * gxk + accJ[k] + inv[k] + i_norm
                                      - xv[k] - gyv[k] - psit);
        xn[k] = xnew; yn[k] = ynew; gn[k] = gxf(xnew);
        anyg = anyg || (gn[k] > 0.0f);
      }

      #pragma unroll
      for (int q = 0; q < 3; ++q) {
        float4 v; v.x=xn[q*4+0]; v.y=xn[q*4+1]; v.z=xn[q*4+2]; v.w=xn[q*4+3];
        ((float4*)(xout + base))[q] = v;
        float4 u; u.x=yn[q*4+0]; u.y=yn[q*4+1]; u.z=yn[q*4+2]; u.w=yn[q*4+3];
        ((float4*)(yb + base))[q] = u;
        float4 o = ((const float4*)(oa + base))[q];
        o.x += gn[q*4+0]; o.y += gn[q*4+1]; o.z += gn[q*4+2]; o.w += gn[q*4+3];
        ((float4*)(oa + base))[q] = o;
      }

      int wfb = __any(anyg) ? 1 : 0;
      if ((tid & 63) == 0) wor[tid >> 6] = wfb;
      __syncthreads();
      if (tid == 0) fout[tile] = wor[0] | wor[1] | wor[2] | wor[3];
    }
    gbar(cnt, gen);
  }

  // final: out = max_k (oa / 16)   (own tiles -> no further barrier needed)
  #pragma unroll 1
  for (int pp = 0; pp < TPB; ++pp) {
    int tile = bid * TPB + pp;
    int b = tile >> 10, rem = tile & 1023;
    int tyb = rem >> 5, txb = rem & 31;
    int r = tid >> 4, c = tid & 15;
    int gh = tyb * 16 + r, gw = txb * 16 + c;
    const float* o = oa + (((size_t)b * HH + gh) * WW + gw) * KK;
    float m = o[0];
    #pragma unroll
    for (int cc = 1; cc < KK; ++cc) m = fmaxf(m, o[cc]);
    out[((size_t)b * HH + gh) * WW + gw] = m * (1.0f / 16.0f);
  }
}

extern "C" void kernel_launch(void* const* d_in, const int* in_sizes, int n_in,
                              void* d_out, int out_size, void* d_ws, size_t ws_size,
                              hipStream_t stream) {
  const float* inp = (const float*)d_in[0];   // (2,512,512,12)
  const float* Wt  = (const float*)d_in[1];   // (15,15,12,12) HWIO
  const float* Jt  = (const float*)d_in[2];   // (15,15,12,12) HWIO
  const float* psi = (const float*)d_in[3];   // (1,1,12,12)

  float* ws = (float*)d_ws;
  const size_t N = (size_t)2 * HH * WW * KK;      // 6,291,456 floats
  float* xA = ws;
  float* xB = ws + N;
  float* yb = ws + 2 * N;
  float* oa = ws + 3 * N;
  int* flags = (int*)(ws + 4 * N);                // 2 * NTILE ints (fallback gates)
  int* gf    = flags + 2 * NTILE;                 // fired flag (MAGIC semantics)
  int* cnt   = gf + 1;                            // software-barrier counter
  int* gen   = gf + 2;                            // software-barrier generation
  float* out = (float*)d_out;

  scan_kernel<<<dim3(NBLK), dim3(NTHR), 0, stream>>>(inp, psi, gf, cnt, gen, out);
  fallback_kernel<<<dim3(NBLK2), dim3(NTHR), 0, stream>>>(
      inp, Wt, Jt, psi, xA, xB, yb, oa, flags, gf, cnt, gen, out);
}